// Round 13
// baseline (507.115 us; speedup 1.0000x reference)
//
#include <hip/hip_runtime.h>
#include <math.h>

#define DIMX   1024
#define NHEADS 16
#define HD     64
#define BATCH  4
#define SEQ    2048
#define NM     (BATCH * NHEADS * SEQ * HD)   // 8388608 elems per Q/K/V tensor

typedef unsigned short ushort_t;
typedef __attribute__((ext_vector_type(8))) short bf16x8;
typedef __attribute__((ext_vector_type(4))) short bf16x4;
typedef __attribute__((ext_vector_type(4))) float f32x4;

#define MFMA16(a, b, c) __builtin_amdgcn_mfma_f32_16x16x32_bf16(a, b, c, 0, 0, 0)

// K=16 bf16 MFMA (A,B = 4 bf16 each). gfx90a+ "_1k" builtin; asm fallback.
#if __has_builtin(__builtin_amdgcn_mfma_f32_16x16x16bf16_1k)
#define MFMA_PV(a, b, c) __builtin_amdgcn_mfma_f32_16x16x16bf16_1k(a, b, c, 0, 0, 0)
#else
static __device__ __forceinline__ f32x4 mfma_pv_asm(bf16x4 a, bf16x4 b, f32x4 c) {
    asm("v_mfma_f32_16x16x16_bf16 %0, %1, %2, %0" : "+v"(c) : "v"(a), "v"(b));
    return c;
}
#define MFMA_PV(a, b, c) mfma_pv_asm(a, b, c)
#endif

// round-to-nearest-even fp32 -> bf16 bits
__device__ __forceinline__ ushort_t f2bf(float x) {
    unsigned u = __float_as_uint(x);
    u += 0x7fffu + ((u >> 16) & 1u);
    return (ushort_t)(u >> 16);
}
__device__ __forceinline__ float bf2f(ushort_t h) {
    return __uint_as_float(((unsigned)h) << 16);
}

// pack two fp32 -> two TRUNCATED bf16 in one dword (lo in low half).
// v_perm_b32: sel bytes 0-3 pick from src1 (=b), 4-7 from src0 (=a).
__device__ __forceinline__ unsigned pack_bf16_trunc(float lo, float hi) {
#if __has_builtin(__builtin_amdgcn_perm)
    return __builtin_amdgcn_perm(__float_as_uint(hi), __float_as_uint(lo), 0x07060302u);
#else
    return (__float_as_uint(lo) >> 16) | (__float_as_uint(hi) & 0xFFFF0000u);
#endif
}
__device__ __forceinline__ float trunc_bf(float x) {
    return __uint_as_float(__float_as_uint(x) & 0xFFFF0000u);
}

// raw v_exp_f32 (no ocml edge-case wrapper) — guarded
__device__ __forceinline__ float fast_exp2(float x) {
#if __has_builtin(__builtin_amdgcn_exp2f)
    return __builtin_amdgcn_exp2f(x);
#else
    return exp2f(x);
#endif
}

// async global->LDS, 16B per lane; LDS base wave-uniform (HW adds lane*16)
#define GLOAD_LDS16(g, l) \
    __builtin_amdgcn_global_load_lds((const __attribute__((address_space(1))) unsigned int*)(g), \
                                     (__attribute__((address_space(3))) unsigned int*)(l), 16, 0, 0)

// ---------------------------------------------------------------------------
// convert_x: split x fp32 -> Xhi, Xlo bf16.  (unchanged)
// ---------------------------------------------------------------------------
__global__ __launch_bounds__(256) void convert_x(
    const float* __restrict__ x, ushort_t* __restrict__ Xh, ushort_t* __restrict__ Xl)
{
    int i = blockIdx.x * 256 + threadIdx.x;
    #pragma unroll
    for (int t = 0; t < 4; t++) {
        int idx = t * 524288 + i;
        f32x4 v = ((const f32x4*)x)[idx];
        ushort4 hi, lo;
        hi.x = f2bf(v[0]); lo.x = f2bf(v[0] - bf2f(hi.x));
        hi.y = f2bf(v[1]); lo.y = f2bf(v[1] - bf2f(hi.y));
        hi.z = f2bf(v[2]); lo.z = f2bf(v[2] - bf2f(hi.z));
        hi.w = f2bf(v[3]); lo.w = f2bf(v[3] - bf2f(hi.w));
        ((ushort4*)Xh)[idx] = hi;
        ((ushort4*)Xl)[idx] = lo;
    }
}

// ---------------------------------------------------------------------------
// convert_w: transpose w[n][d][e] -> Wt[e'][d], split hi/lo bf16. (unchanged)
// ---------------------------------------------------------------------------
__global__ __launch_bounds__(256) void convert_w(
    const float* __restrict__ wk, const float* __restrict__ wq, const float* __restrict__ wv,
    ushort_t* __restrict__ Bqh, ushort_t* __restrict__ Bql, ushort_t* __restrict__ Bvh)
{
    __shared__ float Ts[64][65];
    const int bid = blockIdx.x;
    const int mat = bid >> 8;
    const int rem = bid & 255;
    const int n  = rem >> 4;
    const int dt = rem & 15;
    const float* w = (mat == 0) ? wq : (mat == 1) ? wk : wv;
    const int tid = threadIdx.x;

    #pragma unroll
    for (int t = 0; t < 16; t++) {
        int i = tid + t * 256;
        int r = i >> 6, e = i & 63;
        Ts[r][e] = w[((size_t)n * 1024 + dt * 64 + r) * 64 + e];
    }
    __syncthreads();
    #pragma unroll
    for (int t = 0; t < 16; t++) {
        int i = tid + t * 256;
        int e = i >> 6, r = i & 63;
        float v = Ts[r][e];
        ushort_t hi = f2bf(v);
        size_t o = (size_t)(n * 64 + e) * 1024 + dt * 64 + r;
        if (mat < 2) {
            Bqh[(size_t)mat * 1048576 + o] = hi;
            Bql[(size_t)mat * 1048576 + o] = f2bf(v - bf2f(hi));
        } else {
            Bvh[o] = hi;
        }
    }
}

// ---------------------------------------------------------------------------
// proj_qk: 3-pass split-bf16 MFMA GEMM. (unchanged)
// ---------------------------------------------------------------------------
__global__ __launch_bounds__(256) void proj_qk(
    const ushort_t* __restrict__ Xh, const ushort_t* __restrict__ Xl,
    const ushort_t* __restrict__ Bh, const ushort_t* __restrict__ Bl,
    float* __restrict__ Qf, ushort_t* __restrict__ Khi, ushort_t* __restrict__ Klo)
{
    __shared__ __align__(16) ushort_t Ah[128 * 64];
    __shared__ __align__(16) ushort_t Al[128 * 64];
    __shared__ __align__(16) ushort_t Bhs[128 * 64];
    __shared__ __align__(16) ushort_t Bls[128 * 64];

    const int mt = blockIdx.x, nt = blockIdx.y;
    const int tid = threadIdx.x;
    const int w = tid >> 6, lane = tid & 63, col = lane & 15, quad = lane >> 4;
    const int wm = w & 1, wn = w >> 1;

    f32x4 acc[4][4] = {};

    for (int kc = 0; kc < 1024; kc += 64) {
        __syncthreads();
        #pragma unroll
        for (int i = 0; i < 4; i++) {
            int s = (w * 4 + i) * 64 + lane;
            int r = s >> 3, j = s & 7, g = j ^ (r & 7);
            size_t aoff = (size_t)(mt * 128 + r) * 1024 + kc + g * 8;
            size_t boff = (size_t)(nt * 128 + r) * 1024 + kc + g * 8;
            GLOAD_LDS16(Xh + aoff, Ah  + (size_t)(w * 4 + i) * 512);
            GLOAD_LDS16(Xl + aoff, Al  + (size_t)(w * 4 + i) * 512);
            GLOAD_LDS16(Bh + boff, Bhs + (size_t)(w * 4 + i) * 512);
            GLOAD_LDS16(Bl + boff, Bls + (size_t)(w * 4 + i) * 512);
        }
        __syncthreads();
        #pragma unroll
        for (int kk = 0; kk < 2; kk++) {
            bf16x8 a_h[4], a_l[4], b_h[4], b_l[4];
            const int gi = kk * 4 + quad;
            #pragma unroll
            for (int t = 0; t < 4; t++) {
                int rA = wm * 64 + t * 16 + col;
                int jA = gi ^ (rA & 7);
                a_h[t] = *(const bf16x8*)&Ah[(rA * 8 + jA) * 8];
                a_l[t] = *(const bf16x8*)&Al[(rA * 8 + jA) * 8];
                int rB = wn * 64 + t * 16 + col;
                int jB = gi ^ (rB & 7);
                b_h[t] = *(const bf16x8*)&Bhs[(rB * 8 + jB) * 8];
                b_l[t] = *(const bf16x8*)&Bls[(rB * 8 + jB) * 8];
            }
            #pragma unroll
            for (int t = 0; t < 4; t++)
                #pragma unroll
                for (int u = 0; u < 4; u++) {
                    acc[t][u] = MFMA16(a_h[t], b_h[u], acc[t][u]);
                    acc[t][u] = MFMA16(a_l[t], b_h[u], acc[t][u]);
                    acc[t][u] = MFMA16(a_h[t], b_l[u], acc[t][u]);
                }
        }
    }

    const bool isQ = (nt < 8);
    #pragma unroll
    for (int t = 0; t < 4; t++) {
        #pragma unroll
        for (int u = 0; u < 4; u++) {
            int np = nt * 128 + wn * 64 + u * 16 + col;
            int head = (np >> 6) & 15, e = np & 63;
            #pragma unroll
            for (int rr = 0; rr < 4; rr++) {
                int mm = mt * 128 + wm * 64 + t * 16 + quad * 4 + rr;
                int bi = mm >> 11, l = mm & 2047;
                size_t base = (((size_t)bi * NHEADS + head) * SEQ + l) * HD + e;
                float v = acc[t][u][rr];
                if (isQ) {
                    Qf[base] = v;
                } else {
                    ushort_t hi = f2bf(v);
                    Khi[base] = hi;
                    Klo[base] = f2bf(v - bf2f(hi));
                }
            }
        }
    }
}

// ---------------------------------------------------------------------------
// proj_v: 1-pass bf16, operand-swapped for transposed-V output. (unchanged)
// ---------------------------------------------------------------------------
__global__ __launch_bounds__(256) void proj_v(
    const ushort_t* __restrict__ Wvh, const ushort_t* __restrict__ Xh,
    ushort_t* __restrict__ Vt)
{
    __shared__ __align__(16) ushort_t Ah[128 * 64];
    __shared__ __align__(16) ushort_t Bhs[128 * 64];

    const int mt = blockIdx.x, nt = blockIdx.y;
    const int tid = threadIdx.x;
    const int w = tid >> 6, lane = tid & 63, col = lane & 15, quad = lane >> 4;
    const int wm = w & 1, wn = w >> 1;

    f32x4 acc[4][4] = {};

    for (int kc = 0; kc < 1024; kc += 64) {
        __syncthreads();
        #pragma unroll
        for (int i = 0; i < 4; i++) {
            int s = (w * 4 + i) * 64 + lane;
            int r = s >> 3, j = s & 7, g = j ^ (r & 7);
            size_t aoff = (size_t)(mt * 128 + r) * 1024 + kc + g * 8;
            size_t boff = (size_t)(nt * 128 + r) * 1024 + kc + g * 8;
            GLOAD_LDS16(Wvh + aoff, Ah  + (size_t)(w * 4 + i) * 512);
            GLOAD_LDS16(Xh  + boff, Bhs + (size_t)(w * 4 + i) * 512);
        }
        __syncthreads();
        #pragma unroll
        for (int kk = 0; kk < 2; kk++) {
            bf16x8 a_h[4], b_h[4];
            const int gi = kk * 4 + quad;
            #pragma unroll
            for (int t = 0; t < 4; t++) {
                int rA = wm * 64 + t * 16 + col;
                a_h[t] = *(const bf16x8*)&Ah[(rA * 8 + (gi ^ (rA & 7))) * 8];
                int rB = wn * 64 + t * 16 + col;
                b_h[t] = *(const bf16x8*)&Bhs[(rB * 8 + (gi ^ (rB & 7))) * 8];
            }
            #pragma unroll
            for (int t = 0; t < 4; t++)
                #pragma unroll
                for (int u = 0; u < 4; u++)
                    acc[t][u] = MFMA16(a_h[t], b_h[u], acc[t][u]);
        }
    }

    #pragma unroll
    for (int t = 0; t < 4; t++) {
        #pragma unroll
        for (int rr = 0; rr < 4; rr++) {
            int ep = mt * 128 + wm * 64 + t * 16 + quad * 4 + rr;
            int head = ep >> 6, e = ep & 63;
            #pragma unroll
            for (int u = 0; u < 4; u++) {
                int lg = nt * 128 + wn * 64 + u * 16 + col;
                int bi = lg >> 11, l = lg & 2047;
                Vt[(((size_t)bi * NHEADS + head) * HD + e) * SEQ + l] = f2bf(acc[t][u][rr]);
            }
        }
    }
}

// ---------------------------------------------------------------------------
// Flash attention, operand-swapped, round-22:
//   Base: round-20/21 best (131 us: 8 waves/block, (512,4), XCD remap ->
//   K/V fully L2-resident, FETCH 41 MB floor). r21's dbuf regressed
//   (occupancy 38->33, mild spill) -> single-buffer retained; dbuf closed.
//   ONE change: de-stage Kls and Vts. Stage ONLY Khs (1 gload/chunk,
//   LDS 24->8 KB); Kl and V are read per-lane from GLOBAL inside the
//   ~30% taken path. This is r17's idea, now valid: the XCD remap makes
//   K/V L2-resident (r17's failure was HBM amplification across 8 L2s —
//   FETCH was 330 MB then; now 41 MB). Aggregate line efficiency of the
//   per-lane reads is 100% (each 128B line fully consumed across the
//   t/quad loads). Mappings derived from the LDS path (bit-identical
//   values, same accumulation order):
//     kl(ks,t)   = Kl_g[(ch*64+t*16+col)*64 + ks*32 + quad*8]  (16B)
//     vfrag(u,t) = Vt_g[(u*16+col)*SEQ + ch*64 + t*16 + quad*4] (8B)
//   Effects: skipped chunks (~70%) fetch zero Kl/V; per-chunk staging
//   drain ~3x shorter; kl/vfrag LDS bank conflicts gone.
// ---------------------------------------------------------------------------
__global__ __launch_bounds__(512, 4) void attn_mfma_kernel(
    const float* __restrict__ Qf, const ushort_t* __restrict__ Khi,
    const ushort_t* __restrict__ Klo, const ushort_t* __restrict__ Vt,
    float* __restrict__ out)
{
    __shared__ __align__(16) ushort_t Khs[64 * 64];

    // XCD-aware remap: all qt-blocks of one bn on one XCD (r20-proven,
    // FETCH 215->41 MB)
    const int linear = blockIdx.y * 16 + blockIdx.x;
    const int xcd = linear & 7;
    const int kk_ = linear >> 3;            // 0..127
    const int bn  = xcd + 8 * (kk_ >> 4);   // 0..63
    const int qt  = kk_ & 15;               // 0..15
    const int tid = threadIdx.x;      // 0..511
    const int w    = tid >> 6;        // 0..7
    const int lane = tid & 63;
    const int col  = lane & 15;
    const int quad = lane >> 4;

    const ushort_t* Kh_g = Khi + (size_t)bn * SEQ * HD;
    const ushort_t* Kl_g = Klo + (size_t)bn * SEQ * HD;
    const ushort_t* Vt_g = Vt  + (size_t)bn * HD * SEQ;

    // ---- Q fragments (B operand: n=lane&15=qrow, k=quad*8+j=e), scaled by
    //      log2e/sqrt(64), split hi/lo.
    union { bf16x8 v; short s[8]; } qh[2], ql[2];
    {
        const int qrow = qt * 128 + w * 16 + col;
        const float* qp = Qf + ((size_t)bn * SEQ + qrow) * HD;
        #pragma unroll
        for (int ks = 0; ks < 2; ks++) {
            float qv[8];
            f32x4 a = *(const f32x4*)(qp + ks * 32 + quad * 8);
            f32x4 b = *(const f32x4*)(qp + ks * 32 + quad * 8 + 4);
            qv[0]=a[0]; qv[1]=a[1]; qv[2]=a[2]; qv[3]=a[3];
            qv[4]=b[0]; qv[5]=b[1]; qv[6]=b[2]; qv[7]=b[3];
            #pragma unroll
            for (int j = 0; j < 8; j++) {
                float xsc = qv[j] * (0.125f * 1.44269504088896f);   // log2e/sqrt(64)
                ushort_t hi = f2bf(xsc);
                ushort_t lo = f2bf(xsc - bf2f(hi));
                qh[ks].s[j] = (short)hi;
                ql[ks].s[j] = (short)lo;
            }
        }
    }

    f32x4 O[4] = {};                                      // O^T: [e-tile]
    float m_i = -1e30f;                                   // per-lane (qrow=col)
    float L   = 0.f;                                      // per-lane partial denom

    // per-lane global bases for taken-path reads (L2-resident post-remap)
    const ushort_t* vbase  = Vt_g + (size_t)col * SEQ + quad * 4;
    const ushort_t* klbase = Kl_g + (size_t)col * HD + quad * 8;

    for (int ch = 0; ch < 32; ch++) {
        __syncthreads();   // previous chunk fully consumed
        {
            // granule G = tid (0..511); each of 8 waves stages 1/8 of Khs
            int G   = tid;
            int key = G >> 3;
            int blk = (G & 7) ^ (key & 7);                 // swizzled 8-elem block
            size_t koff = (size_t)(ch * 64 + key) * HD + blk * 8;
            GLOAD_LDS16(Kh_g + koff, Khs + w * 512);
        }
        __syncthreads();   // staged data visible

        // ---- pass 1 only: St = Kh Qh^T (8 MFMAs)
        f32x4 St[4] = {};                                 // [key-tile]
        #pragma unroll
        for (int ks = 0; ks < 2; ks++) {
            #pragma unroll
            for (int t = 0; t < 4; t++) {
                int key = t * 16 + col;
                int g = key * 8 + ((ks * 4 + quad) ^ (key & 7));
                bf16x8 kh = *(const bf16x8*)&Khs[g * 8];
                St[t] = MFMA16(kh, qh[ks].v, St[t]);
            }
        }

        // ---- approx chunk max (serial chain, proven schedule)
        float mx = St[0][0];
        #pragma unroll
        for (int t = 0; t < 4; t++)
            #pragma unroll
            for (int r = 0; r < 4; r++) mx = fmaxf(mx, St[t][r]);
        mx = fmaxf(mx, __shfl_xor(mx, 16));
        mx = fmaxf(mx, __shfl_xor(mx, 32));

        // ---- gate: skip iff all rows' approx max <= m_i - 46.
        //      |mx_exact - mx_approx| <= 2^-8*sum|q_e k_e| << 16 units, so
        //      skipping implies mx_exact <= m_i - 30 (r13 guarantee).
        if (__any(mx > m_i - 46.0f)) {
            // V^T fragments from GLOBAL (L2), issued early: latency hides
            // under passes 2-3 + softmax. Same values as the old LDS path.
            bf16x4 vfrag[4][4];                           // [e-tile][key-tile]
            {
                const ushort_t* vp = vbase + ch * 64;
                #pragma unroll
                for (int u = 0; u < 4; u++)
                    #pragma unroll
                    for (int t = 0; t < 4; t++)
                        vfrag[u][t] = *(const bf16x4*)(vp + (size_t)u * 16 * SEQ + t * 16);
            }

            // passes 2-3: St += Kh Ql^T + Kl Qh^T; Kl from GLOBAL (L2)
            {
                const ushort_t* klp = klbase + (size_t)(ch * 64) * HD;
                #pragma unroll
                for (int ks = 0; ks < 2; ks++) {
                    #pragma unroll
                    for (int t = 0; t < 4; t++) {
                        int key = t * 16 + col;
                        int g = key * 8 + ((ks * 4 + quad) ^ (key & 7));
                        bf16x8 kh = *(const bf16x8*)&Khs[g * 8];
                        bf16x8 kl = *(const bf16x8*)(klp + (size_t)(t * 16) * HD + ks * 32);
                        St[t] = MFMA16(kh, ql[ks].v, St[t]);
                        St[t] = MFMA16(kl, qh[ks].v, St[t]);
                    }
                }
            }
            // exact chunk max
            float mxe = St[0][0];
            #pragma unroll
            for (int t = 0; t < 4; t++)
                #pragma unroll
                for (int r = 0; r < 4; r++) mxe = fmaxf(mxe, St[t][r]);
            mxe = fmaxf(mxe, __shfl_xor(mxe, 16));
            mxe = fmaxf(mxe, __shfl_xor(mxe, 32));
            float mnew = fmaxf(m_i, mxe);
            float al   = fast_exp2(m_i - mnew);
            m_i = mnew;

            float psum = 0.f;
            bf16x4 pf[4];                                 // P^T B-frags per key-tile
            #pragma unroll
            for (int t = 0; t < 4; t++) {
                float p0 = fast_exp2(St[t][0] - mnew);
                float p1 = fast_exp2(St[t][1] - mnew);
                float p2 = fast_exp2(St[t][2] - mnew);
                float p3 = fast_exp2(St[t][3] - mnew);
                // truncated-bf16 P; psum over the SAME truncated values
                psum += trunc_bf(p0) + trunc_bf(p1) + trunc_bf(p2) + trunc_bf(p3);
                union { unsigned u[2]; bf16x4 v; } pk;
                pk.u[0] = pack_bf16_trunc(p0, p1);
                pk.u[1] = pack_bf16_trunc(p2, p3);
                pf[t] = pk.v;
            }
            L = L * al + psum;                            // per-lane partial; al row-uniform
            #pragma unroll
            for (int u = 0; u < 4; u++) {
                O[u][0] *= al; O[u][1] *= al;
                O[u][2] *= al; O[u][3] *= al;
            }
            #pragma unroll
            for (int t = 0; t < 4; t++)
                #pragma unroll
                for (int u = 0; u < 4; u++)
                    O[u] = MFMA_PV(vfrag[u][t], pf[t], O[u]);
        }
    }

    // ---- epilogue: finish L across quads (2 shuffles), write float4 along e
    const int b = bn >> 4, n = bn & 15;
    {
        float Lr = L;
        Lr += __shfl_xor(Lr, 16);
        Lr += __shfl_xor(Lr, 32);
        float inv = 1.0f / Lr;
        int l = qt * 128 + w * 16 + col;
        size_t base = ((size_t)(b * SEQ + l)) * (NHEADS * HD) + n * HD;
        #pragma unroll
        for (int u = 0; u < 4; u++) {
            f32x4 o;
            o[0] = O[u][0] * inv; o[1] = O[u][1] * inv;
            o[2] = O[u][2] * inv; o[3] = O[u][3] * inv;
            *(f32x4*)&out[base + u * 16 + quad * 4] = o;
        }
    }
}

// ---------------------------------------------------------------------------
extern "C" void kernel_launch(void* const* d_in, const int* in_sizes, int n_in,
                              void* d_out, int out_size, void* d_ws, size_t ws_size,
                              hipStream_t stream) {
    const float* x  = (const float*)d_in[0];
    const float* wk = (const float*)d_in[1];
    const float* wq = (const float*)d_in[2];
    const float* wv = (const float*)d_in[3];
    float* out = (float*)d_out;

    // ws layout (111 MB): Xh | Xl (aliased by Vt after proj_qk) | Bqh | Bql | Bvh | Qf | Khi | Klo
    ushort_t* Xh  = (ushort_t*)d_ws;
    ushort_t* Xl  = Xh + NM;
    ushort_t* Vt  = Xl;                      // alias: Xl dead once proj_qk finishes
    ushort_t* Bqh = Xl + NM;                 // [2048][1024]
    ushort_t* Bql = Bqh + 2097152;
    ushort_t* Bvh = Bql + 2097152;           // [1024][1024]
    float*    Qf  = (float*)(Bvh + 1048576);
    ushort_t* Khi = (ushort_t*)(Qf + NM);
    ushort_t* Klo = Khi + NM;

    convert_x<<<2048, 256, 0, stream>>>(x, Xh, Xl);
    convert_w<<<768, 256, 0, stream>>>(wk, wq, wv, Bqh, Bql, Bvh);
    proj_qk<<<dim3(64, 16), 256, 0, stream>>>(Xh, Xl, Bqh, Bql, Qf, Khi, Klo);
    proj_v<<<dim3(8, 64), 256, 0, stream>>>(Bvh, Xh, Vt);
    attn_mfma_kernel<<<dim3(16, 64), 512, 0, stream>>>(Qf, Khi, Klo, Vt, out);
}

// Round 14
// 327.020 us; speedup vs baseline: 1.5507x; 1.5507x over previous
//
#include <hip/hip_runtime.h>
#include <math.h>

#define DIMX   1024
#define NHEADS 16
#define HD     64
#define BATCH  4
#define SEQ    2048
#define NM     (BATCH * NHEADS * SEQ * HD)   // 8388608 elems per Q/K/V tensor

typedef unsigned short ushort_t;
typedef __attribute__((ext_vector_type(8))) short bf16x8;
typedef __attribute__((ext_vector_type(4))) short bf16x4;
typedef __attribute__((ext_vector_type(4))) float f32x4;

#define MFMA16(a, b, c) __builtin_amdgcn_mfma_f32_16x16x32_bf16(a, b, c, 0, 0, 0)

// K=16 bf16 MFMA (A,B = 4 bf16 each). gfx90a+ "_1k" builtin; asm fallback.
#if __has_builtin(__builtin_amdgcn_mfma_f32_16x16x16bf16_1k)
#define MFMA_PV(a, b, c) __builtin_amdgcn_mfma_f32_16x16x16bf16_1k(a, b, c, 0, 0, 0)
#else
static __device__ __forceinline__ f32x4 mfma_pv_asm(bf16x4 a, bf16x4 b, f32x4 c) {
    asm("v_mfma_f32_16x16x16_bf16 %0, %1, %2, %0" : "+v"(c) : "v"(a), "v"(b));
    return c;
}
#define MFMA_PV(a, b, c) mfma_pv_asm(a, b, c)
#endif

// round-to-nearest-even fp32 -> bf16 bits
__device__ __forceinline__ ushort_t f2bf(float x) {
    unsigned u = __float_as_uint(x);
    u += 0x7fffu + ((u >> 16) & 1u);
    return (ushort_t)(u >> 16);
}
__device__ __forceinline__ float bf2f(ushort_t h) {
    return __uint_as_float(((unsigned)h) << 16);
}

// pack two fp32 -> two TRUNCATED bf16 in one dword (lo in low half).
// v_perm_b32: sel bytes 0-3 pick from src1 (=b), 4-7 from src0 (=a).
__device__ __forceinline__ unsigned pack_bf16_trunc(float lo, float hi) {
#if __has_builtin(__builtin_amdgcn_perm)
    return __builtin_amdgcn_perm(__float_as_uint(hi), __float_as_uint(lo), 0x07060302u);
#else
    return (__float_as_uint(lo) >> 16) | (__float_as_uint(hi) & 0xFFFF0000u);
#endif
}
__device__ __forceinline__ float trunc_bf(float x) {
    return __uint_as_float(__float_as_uint(x) & 0xFFFF0000u);
}

// raw v_exp_f32 (no ocml edge-case wrapper) — guarded
__device__ __forceinline__ float fast_exp2(float x) {
#if __has_builtin(__builtin_amdgcn_exp2f)
    return __builtin_amdgcn_exp2f(x);
#else
    return exp2f(x);
#endif
}

// async global->LDS, 16B per lane; LDS base wave-uniform (HW adds lane*16)
#define GLOAD_LDS16(g, l) \
    __builtin_amdgcn_global_load_lds((const __attribute__((address_space(1))) unsigned int*)(g), \
                                     (__attribute__((address_space(3))) unsigned int*)(l), 16, 0, 0)

// ---------------------------------------------------------------------------
// convert_x: split x fp32 -> Xhi, Xlo bf16.  (unchanged)
// ---------------------------------------------------------------------------
__global__ __launch_bounds__(256) void convert_x(
    const float* __restrict__ x, ushort_t* __restrict__ Xh, ushort_t* __restrict__ Xl)
{
    int i = blockIdx.x * 256 + threadIdx.x;
    #pragma unroll
    for (int t = 0; t < 4; t++) {
        int idx = t * 524288 + i;
        f32x4 v = ((const f32x4*)x)[idx];
        ushort4 hi, lo;
        hi.x = f2bf(v[0]); lo.x = f2bf(v[0] - bf2f(hi.x));
        hi.y = f2bf(v[1]); lo.y = f2bf(v[1] - bf2f(hi.y));
        hi.z = f2bf(v[2]); lo.z = f2bf(v[2] - bf2f(hi.z));
        hi.w = f2bf(v[3]); lo.w = f2bf(v[3] - bf2f(hi.w));
        ((ushort4*)Xh)[idx] = hi;
        ((ushort4*)Xl)[idx] = lo;
    }
}

// ---------------------------------------------------------------------------
// convert_w: transpose w[n][d][e] -> Wt[e'][d], split hi/lo bf16. (unchanged)
// ---------------------------------------------------------------------------
__global__ __launch_bounds__(256) void convert_w(
    const float* __restrict__ wk, const float* __restrict__ wq, const float* __restrict__ wv,
    ushort_t* __restrict__ Bqh, ushort_t* __restrict__ Bql, ushort_t* __restrict__ Bvh)
{
    __shared__ float Ts[64][65];
    const int bid = blockIdx.x;
    const int mat = bid >> 8;
    const int rem = bid & 255;
    const int n  = rem >> 4;
    const int dt = rem & 15;
    const float* w = (mat == 0) ? wq : (mat == 1) ? wk : wv;
    const int tid = threadIdx.x;

    #pragma unroll
    for (int t = 0; t < 16; t++) {
        int i = tid + t * 256;
        int r = i >> 6, e = i & 63;
        Ts[r][e] = w[((size_t)n * 1024 + dt * 64 + r) * 64 + e];
    }
    __syncthreads();
    #pragma unroll
    for (int t = 0; t < 16; t++) {
        int i = tid + t * 256;
        int e = i >> 6, r = i & 63;
        float v = Ts[r][e];
        ushort_t hi = f2bf(v);
        size_t o = (size_t)(n * 64 + e) * 1024 + dt * 64 + r;
        if (mat < 2) {
            Bqh[(size_t)mat * 1048576 + o] = hi;
            Bql[(size_t)mat * 1048576 + o] = f2bf(v - bf2f(hi));
        } else {
            Bvh[o] = hi;
        }
    }
}

// ---------------------------------------------------------------------------
// proj_qk: 3-pass split-bf16 MFMA GEMM. Round-23: 512 threads (8 waves),
//   same 128x128 tile / dataflow / staging swizzle / MFMA order.
//   256-thr version had 64KB LDS -> 2 blocks x 4 waves = 2 waves/SIMD, the
//   lowest occupancy in the pipeline. 8 waves: per-wave output 64x32
//   (acc[4][2], ~100 VGPR <= 128 cap), occupancy 2 blocks x 8 waves =
//   4 waves/SIMD (2x). Bit-identical output (same per-element MFMA order).
// ---------------------------------------------------------------------------
__global__ __launch_bounds__(512, 4) void proj_qk(
    const ushort_t* __restrict__ Xh, const ushort_t* __restrict__ Xl,
    const ushort_t* __restrict__ Bh, const ushort_t* __restrict__ Bl,
    float* __restrict__ Qf, ushort_t* __restrict__ Khi, ushort_t* __restrict__ Klo)
{
    __shared__ __align__(16) ushort_t Ah[128 * 64];
    __shared__ __align__(16) ushort_t Al[128 * 64];
    __shared__ __align__(16) ushort_t Bhs[128 * 64];
    __shared__ __align__(16) ushort_t Bls[128 * 64];

    const int mt = blockIdx.x, nt = blockIdx.y;
    const int tid = threadIdx.x;                 // 0..511
    const int w = tid >> 6, lane = tid & 63, col = lane & 15, quad = lane >> 4;
    const int wm = w & 1, wn = w >> 1;           // wm 0..1 (64-row half), wn 0..3 (32-col quarter)

    f32x4 acc[4][2] = {};

    for (int kc = 0; kc < 1024; kc += 64) {
        __syncthreads();
        #pragma unroll
        for (int i = 0; i < 2; i++) {
            int s = (w * 2 + i) * 64 + lane;     // granule 0..1023
            int r = s >> 3, j = s & 7, g = j ^ (r & 7);
            size_t aoff = (size_t)(mt * 128 + r) * 1024 + kc + g * 8;
            size_t boff = (size_t)(nt * 128 + r) * 1024 + kc + g * 8;
            GLOAD_LDS16(Xh + aoff, Ah  + (size_t)(w * 2 + i) * 512);
            GLOAD_LDS16(Xl + aoff, Al  + (size_t)(w * 2 + i) * 512);
            GLOAD_LDS16(Bh + boff, Bhs + (size_t)(w * 2 + i) * 512);
            GLOAD_LDS16(Bl + boff, Bls + (size_t)(w * 2 + i) * 512);
        }
        __syncthreads();
        #pragma unroll
        for (int kk = 0; kk < 2; kk++) {
            bf16x8 a_h[4], a_l[4], b_h[2], b_l[2];
            const int gi = kk * 4 + quad;
            #pragma unroll
            for (int t = 0; t < 4; t++) {
                int rA = wm * 64 + t * 16 + col;
                int jA = gi ^ (rA & 7);
                a_h[t] = *(const bf16x8*)&Ah[(rA * 8 + jA) * 8];
                a_l[t] = *(const bf16x8*)&Al[(rA * 8 + jA) * 8];
            }
            #pragma unroll
            for (int u = 0; u < 2; u++) {
                int rB = wn * 32 + u * 16 + col;
                int jB = gi ^ (rB & 7);
                b_h[u] = *(const bf16x8*)&Bhs[(rB * 8 + jB) * 8];
                b_l[u] = *(const bf16x8*)&Bls[(rB * 8 + jB) * 8];
            }
            #pragma unroll
            for (int t = 0; t < 4; t++)
                #pragma unroll
                for (int u = 0; u < 2; u++) {
                    acc[t][u] = MFMA16(a_h[t], b_h[u], acc[t][u]);
                    acc[t][u] = MFMA16(a_l[t], b_h[u], acc[t][u]);
                    acc[t][u] = MFMA16(a_h[t], b_l[u], acc[t][u]);
                }
        }
    }

    const bool isQ = (nt < 8);
    #pragma unroll
    for (int t = 0; t < 4; t++) {
        #pragma unroll
        for (int u = 0; u < 2; u++) {
            int np = nt * 128 + wn * 32 + u * 16 + col;
            int head = (np >> 6) & 15, e = np & 63;
            #pragma unroll
            for (int rr = 0; rr < 4; rr++) {
                int mm = mt * 128 + wm * 64 + t * 16 + quad * 4 + rr;
                int bi = mm >> 11, l = mm & 2047;
                size_t base = (((size_t)bi * NHEADS + head) * SEQ + l) * HD + e;
                float v = acc[t][u][rr];
                if (isQ) {
                    Qf[base] = v;
                } else {
                    ushort_t hi = f2bf(v);
                    Khi[base] = hi;
                    Klo[base] = f2bf(v - bf2f(hi));
                }
            }
        }
    }
}

// ---------------------------------------------------------------------------
// proj_v: 1-pass bf16, operand-swapped for transposed-V output. (unchanged)
// ---------------------------------------------------------------------------
__global__ __launch_bounds__(256) void proj_v(
    const ushort_t* __restrict__ Wvh, const ushort_t* __restrict__ Xh,
    ushort_t* __restrict__ Vt)
{
    __shared__ __align__(16) ushort_t Ah[128 * 64];
    __shared__ __align__(16) ushort_t Bhs[128 * 64];

    const int mt = blockIdx.x, nt = blockIdx.y;
    const int tid = threadIdx.x;
    const int w = tid >> 6, lane = tid & 63, col = lane & 15, quad = lane >> 4;
    const int wm = w & 1, wn = w >> 1;

    f32x4 acc[4][4] = {};

    for (int kc = 0; kc < 1024; kc += 64) {
        __syncthreads();
        #pragma unroll
        for (int i = 0; i < 4; i++) {
            int s = (w * 4 + i) * 64 + lane;
            int r = s >> 3, j = s & 7, g = j ^ (r & 7);
            size_t aoff = (size_t)(mt * 128 + r) * 1024 + kc + g * 8;
            size_t boff = (size_t)(nt * 128 + r) * 1024 + kc + g * 8;
            GLOAD_LDS16(Wvh + aoff, Ah  + (size_t)(w * 4 + i) * 512);
            GLOAD_LDS16(Xh  + boff, Bhs + (size_t)(w * 4 + i) * 512);
        }
        __syncthreads();
        #pragma unroll
        for (int kk = 0; kk < 2; kk++) {
            bf16x8 a_h[4], b_h[4];
            const int gi = kk * 4 + quad;
            #pragma unroll
            for (int t = 0; t < 4; t++) {
                int rA = wm * 64 + t * 16 + col;
                a_h[t] = *(const bf16x8*)&Ah[(rA * 8 + (gi ^ (rA & 7))) * 8];
                int rB = wn * 64 + t * 16 + col;
                b_h[t] = *(const bf16x8*)&Bhs[(rB * 8 + (gi ^ (rB & 7))) * 8];
            }
            #pragma unroll
            for (int t = 0; t < 4; t++)
                #pragma unroll
                for (int u = 0; u < 4; u++)
                    acc[t][u] = MFMA16(a_h[t], b_h[u], acc[t][u]);
        }
    }

    #pragma unroll
    for (int t = 0; t < 4; t++) {
        #pragma unroll
        for (int rr = 0; rr < 4; rr++) {
            int ep = mt * 128 + wm * 64 + t * 16 + quad * 4 + rr;
            int head = ep >> 6, e = ep & 63;
            #pragma unroll
            for (int u = 0; u < 4; u++) {
                int lg = nt * 128 + wn * 64 + u * 16 + col;
                int bi = lg >> 11, l = lg & 2047;
                Vt[(((size_t)bi * NHEADS + head) * HD + e) * SEQ + l] = f2bf(acc[t][u][rr]);
            }
        }
    }
}

// ---------------------------------------------------------------------------
// Flash attention, operand-swapped — EXACT round-20 (r11) version, the
// proven best: 8 waves/block, (512,4), XCD remap (FETCH 41 MB floor),
// two-stage QK gate, negligible-chunk skip, single-buffered LDS staging.
// r22's de-staging regressed (per-lane scattered L2 reads: 16 lines/instr
// replay, MfmaUtil 26->10) — coalesced global_load_lds staging is the only
// viable K/V feed. Reverted verbatim.
// ---------------------------------------------------------------------------
__global__ __launch_bounds__(512, 4) void attn_mfma_kernel(
    const float* __restrict__ Qf, const ushort_t* __restrict__ Khi,
    const ushort_t* __restrict__ Klo, const ushort_t* __restrict__ Vt,
    float* __restrict__ out)
{
    __shared__ __align__(16) ushort_t Khs[64 * 64];
    __shared__ __align__(16) ushort_t Kls[64 * 64];
    __shared__ __align__(16) ushort_t Vts[64 * 64];

    // XCD-aware remap: all qt-blocks of one bn on one XCD (r20-proven,
    // FETCH 215->41 MB)
    const int linear = blockIdx.y * 16 + blockIdx.x;
    const int xcd = linear & 7;
    const int kk_ = linear >> 3;            // 0..127
    const int bn  = xcd + 8 * (kk_ >> 4);   // 0..63
    const int qt  = kk_ & 15;               // 0..15
    const int tid = threadIdx.x;      // 0..511
    const int w    = tid >> 6;        // 0..7
    const int lane = tid & 63;
    const int col  = lane & 15;
    const int quad = lane >> 4;

    const ushort_t* Kh_g = Khi + (size_t)bn * SEQ * HD;
    const ushort_t* Kl_g = Klo + (size_t)bn * SEQ * HD;
    const ushort_t* Vt_g = Vt  + (size_t)bn * HD * SEQ;

    // ---- Q fragments (B operand: n=lane&15=qrow, k=quad*8+j=e), scaled by
    //      log2e/sqrt(64), split hi/lo.
    union { bf16x8 v; short s[8]; } qh[2], ql[2];
    {
        const int qrow = qt * 128 + w * 16 + col;
        const float* qp = Qf + ((size_t)bn * SEQ + qrow) * HD;
        #pragma unroll
        for (int ks = 0; ks < 2; ks++) {
            float qv[8];
            f32x4 a = *(const f32x4*)(qp + ks * 32 + quad * 8);
            f32x4 b = *(const f32x4*)(qp + ks * 32 + quad * 8 + 4);
            qv[0]=a[0]; qv[1]=a[1]; qv[2]=a[2]; qv[3]=a[3];
            qv[4]=b[0]; qv[5]=b[1]; qv[6]=b[2]; qv[7]=b[3];
            #pragma unroll
            for (int j = 0; j < 8; j++) {
                float xsc = qv[j] * (0.125f * 1.44269504088896f);   // log2e/sqrt(64)
                ushort_t hi = f2bf(xsc);
                ushort_t lo = f2bf(xsc - bf2f(hi));
                qh[ks].s[j] = (short)hi;
                ql[ks].s[j] = (short)lo;
            }
        }
    }

    f32x4 O[4] = {};                                      // O^T: [e-tile]
    float m_i = -1e30f;                                   // per-lane (qrow=col)
    float L   = 0.f;                                      // per-lane partial denom

    for (int ch = 0; ch < 32; ch++) {
        __syncthreads();   // previous chunk fully consumed
        {
            // granule G = tid (0..511); each of 8 waves stages 1/8 of each buf
            int G   = tid;
            int key = G >> 3;                              // key (K) / e (V)
            int blk = (G & 7) ^ (key & 7);                 // swizzled 8-elem block
            size_t koff = (size_t)(ch * 64 + key) * HD + blk * 8;
            size_t voff = (size_t)key * SEQ + ch * 64 + blk * 8;
            GLOAD_LDS16(Kh_g + koff, Khs + w * 512);
            GLOAD_LDS16(Kl_g + koff, Kls + w * 512);
            GLOAD_LDS16(Vt_g + voff, Vts + w * 512);
        }
        __syncthreads();   // staged data visible

        // ---- pass 1 only: St = Kh Qh^T (8 MFMAs)
        f32x4 St[4] = {};                                 // [key-tile]
        #pragma unroll
        for (int ks = 0; ks < 2; ks++) {
            #pragma unroll
            for (int t = 0; t < 4; t++) {
                int key = t * 16 + col;
                int g = key * 8 + ((ks * 4 + quad) ^ (key & 7));
                bf16x8 kh = *(const bf16x8*)&Khs[g * 8];
                St[t] = MFMA16(kh, qh[ks].v, St[t]);
            }
        }

        // ---- approx chunk max (serial chain, proven schedule)
        float mx = St[0][0];
        #pragma unroll
        for (int t = 0; t < 4; t++)
            #pragma unroll
            for (int r = 0; r < 4; r++) mx = fmaxf(mx, St[t][r]);
        mx = fmaxf(mx, __shfl_xor(mx, 16));
        mx = fmaxf(mx, __shfl_xor(mx, 32));

        // ---- gate: skip iff all rows' approx max <= m_i - 46.
        //      |mx_exact - mx_approx| <= 2^-8*sum|q_e k_e| << 16 units, so
        //      skipping implies mx_exact <= m_i - 30 (r13 guarantee).
        if (__any(mx > m_i - 46.0f)) {
            // passes 2-3: St += Kh Ql^T + Kl Qh^T (16 MFMAs)
            #pragma unroll
            for (int ks = 0; ks < 2; ks++) {
                #pragma unroll
                for (int t = 0; t < 4; t++) {
                    int key = t * 16 + col;
                    int g = key * 8 + ((ks * 4 + quad) ^ (key & 7));
                    bf16x8 kh = *(const bf16x8*)&Khs[g * 8];
                    bf16x8 kl = *(const bf16x8*)&Kls[g * 8];
                    St[t] = MFMA16(kh, ql[ks].v, St[t]);
                    St[t] = MFMA16(kl, qh[ks].v, St[t]);
                }
            }
            // exact chunk max
            float mxe = St[0][0];
            #pragma unroll
            for (int t = 0; t < 4; t++)
                #pragma unroll
                for (int r = 0; r < 4; r++) mxe = fmaxf(mxe, St[t][r]);
            mxe = fmaxf(mxe, __shfl_xor(mxe, 16));
            mxe = fmaxf(mxe, __shfl_xor(mxe, 32));
            float mnew = fmaxf(m_i, mxe);
            float al   = fast_exp2(m_i - mnew);
            m_i = mnew;

            // V^T A-fragments (m=lane&15=e, k=quad*4+j=key): b64 reads
            bf16x4 vfrag[4][4];                           // [e-tile][key-tile]
            #pragma unroll
            for (int u = 0; u < 4; u++) {
                int rowbase = (u * 16 + col) * 64;
                #pragma unroll
                for (int t = 0; t < 4; t++) {
                    int g = (t * 2 + (quad >> 1)) ^ (col & 7);
                    vfrag[u][t] = *(const bf16x4*)&Vts[rowbase + g * 8 + (quad & 1) * 4];
                }
            }

            float psum = 0.f;
            bf16x4 pf[4];                                 // P^T B-frags per key-tile
            #pragma unroll
            for (int t = 0; t < 4; t++) {
                float p0 = fast_exp2(St[t][0] - mnew);
                float p1 = fast_exp2(St[t][1] - mnew);
                float p2 = fast_exp2(St[t][2] - mnew);
                float p3 = fast_exp2(St[t][3] - mnew);
                // truncated-bf16 P; psum over the SAME truncated values
                psum += trunc_bf(p0) + trunc_bf(p1) + trunc_bf(p2) + trunc_bf(p3);
                union { unsigned u[2]; bf16x4 v; } pk;
                pk.u[0] = pack_bf16_trunc(p0, p1);
                pk.u[1] = pack_bf16_trunc(p2, p3);
                pf[t] = pk.v;
            }
            L = L * al + psum;                            // per-lane partial; al row-uniform
            #pragma unroll
            for (int u = 0; u < 4; u++) {
                O[u][0] *= al; O[u][1] *= al;
                O[u][2] *= al; O[u][3] *= al;
            }
            #pragma unroll
            for (int t = 0; t < 4; t++)
                #pragma unroll
                for (int u = 0; u < 4; u++)
                    O[u] = MFMA_PV(vfrag[u][t], pf[t], O[u]);
        }
    }

    // ---- epilogue: finish L across quads (2 shuffles), write float4 along e
    const int b = bn >> 4, n = bn & 15;
    {
        float Lr = L;
        Lr += __shfl_xor(Lr, 16);
        Lr += __shfl_xor(Lr, 32);
        float inv = 1.0f / Lr;
        int l = qt * 128 + w * 16 + col;
        size_t base = ((size_t)(b * SEQ + l)) * (NHEADS * HD) + n * HD;
        #pragma unroll
        for (int u = 0; u < 4; u++) {
            f32x4 o;
            o[0] = O[u][0] * inv; o[1] = O[u][1] * inv;
            o[2] = O[u][2] * inv; o[3] = O[u][3] * inv;
            *(f32x4*)&out[base + u * 16 + quad * 4] = o;
        }
    }
}

// ---------------------------------------------------------------------------
extern "C" void kernel_launch(void* const* d_in, const int* in_sizes, int n_in,
                              void* d_out, int out_size, void* d_ws, size_t ws_size,
                              hipStream_t stream) {
    const float* x  = (const float*)d_in[0];
    const float* wk = (const float*)d_in[1];
    const float* wq = (const float*)d_in[2];
    const float* wv = (const float*)d_in[3];
    float* out = (float*)d_out;

    // ws layout (111 MB): Xh | Xl (aliased by Vt after proj_qk) | Bqh | Bql | Bvh | Qf | Khi | Klo
    ushort_t* Xh  = (ushort_t*)d_ws;
    ushort_t* Xl  = Xh + NM;
    ushort_t* Vt  = Xl;                      // alias: Xl dead once proj_qk finishes
    ushort_t* Bqh = Xl + NM;                 // [2048][1024]
    ushort_t* Bql = Bqh + 2097152;
    ushort_t* Bvh = Bql + 2097152;           // [1024][1024]
    float*    Qf  = (float*)(Bvh + 1048576);
    ushort_t* Khi = (ushort_t*)(Qf + NM);
    ushort_t* Klo = Khi + NM;

    convert_x<<<2048, 256, 0, stream>>>(x, Xh, Xl);
    convert_w<<<768, 256, 0, stream>>>(wk, wq, wv, Bqh, Bql, Bvh);
    proj_qk<<<dim3(64, 16), 512, 0, stream>>>(Xh, Xl, Bqh, Bql, Qf, Khi, Klo);
    proj_v<<<dim3(8, 64), 256, 0, stream>>>(Bvh, Xh, Vt);
    attn_mfma_kernel<<<dim3(16, 64), 512, 0, stream>>>(Qf, Khi, Klo, Vt, out);
}

// Round 15
// 316.799 us; speedup vs baseline: 1.6007x; 1.0323x over previous
//
#include <hip/hip_runtime.h>
#include <math.h>

#define DIMX   1024
#define NHEADS 16
#define HD     64
#define BATCH  4
#define SEQ    2048
#define NM     (BATCH * NHEADS * SEQ * HD)   // 8388608 elems per Q/K/V tensor

typedef unsigned short ushort_t;
typedef __attribute__((ext_vector_type(8))) short bf16x8;
typedef __attribute__((ext_vector_type(4))) short bf16x4;
typedef __attribute__((ext_vector_type(4))) float f32x4;

#define MFMA16(a, b, c) __builtin_amdgcn_mfma_f32_16x16x32_bf16(a, b, c, 0, 0, 0)

// K=16 bf16 MFMA (A,B = 4 bf16 each). gfx90a+ "_1k" builtin; asm fallback.
#if __has_builtin(__builtin_amdgcn_mfma_f32_16x16x16bf16_1k)
#define MFMA_PV(a, b, c) __builtin_amdgcn_mfma_f32_16x16x16bf16_1k(a, b, c, 0, 0, 0)
#else
static __device__ __forceinline__ f32x4 mfma_pv_asm(bf16x4 a, bf16x4 b, f32x4 c) {
    asm("v_mfma_f32_16x16x16_bf16 %0, %1, %2, %0" : "+v"(c) : "v"(a), "v"(b));
    return c;
}
#define MFMA_PV(a, b, c) mfma_pv_asm(a, b, c)
#endif

// round-to-nearest-even fp32 -> bf16 bits
__device__ __forceinline__ ushort_t f2bf(float x) {
    unsigned u = __float_as_uint(x);
    u += 0x7fffu + ((u >> 16) & 1u);
    return (ushort_t)(u >> 16);
}
__device__ __forceinline__ float bf2f(ushort_t h) {
    return __uint_as_float(((unsigned)h) << 16);
}

// pack two fp32 -> two TRUNCATED bf16 in one dword (lo in low half).
// v_perm_b32: sel bytes 0-3 pick from src1 (=b), 4-7 from src0 (=a).
__device__ __forceinline__ unsigned pack_bf16_trunc(float lo, float hi) {
#if __has_builtin(__builtin_amdgcn_perm)
    return __builtin_amdgcn_perm(__float_as_uint(hi), __float_as_uint(lo), 0x07060302u);
#else
    return (__float_as_uint(lo) >> 16) | (__float_as_uint(hi) & 0xFFFF0000u);
#endif
}
__device__ __forceinline__ float trunc_bf(float x) {
    return __uint_as_float(__float_as_uint(x) & 0xFFFF0000u);
}

// raw v_exp_f32 (no ocml edge-case wrapper) — guarded
__device__ __forceinline__ float fast_exp2(float x) {
#if __has_builtin(__builtin_amdgcn_exp2f)
    return __builtin_amdgcn_exp2f(x);
#else
    return exp2f(x);
#endif
}

// async global->LDS, 16B per lane; LDS base wave-uniform (HW adds lane*16)
#define GLOAD_LDS16(g, l) \
    __builtin_amdgcn_global_load_lds((const __attribute__((address_space(1))) unsigned int*)(g), \
                                     (__attribute__((address_space(3))) unsigned int*)(l), 16, 0, 0)

// ---------------------------------------------------------------------------
// convert_x: split x fp32 -> Xhi, Xlo bf16.  (unchanged)
// ---------------------------------------------------------------------------
__global__ __launch_bounds__(256) void convert_x(
    const float* __restrict__ x, ushort_t* __restrict__ Xh, ushort_t* __restrict__ Xl)
{
    int i = blockIdx.x * 256 + threadIdx.x;
    #pragma unroll
    for (int t = 0; t < 4; t++) {
        int idx = t * 524288 + i;
        f32x4 v = ((const f32x4*)x)[idx];
        ushort4 hi, lo;
        hi.x = f2bf(v[0]); lo.x = f2bf(v[0] - bf2f(hi.x));
        hi.y = f2bf(v[1]); lo.y = f2bf(v[1] - bf2f(hi.y));
        hi.z = f2bf(v[2]); lo.z = f2bf(v[2] - bf2f(hi.z));
        hi.w = f2bf(v[3]); lo.w = f2bf(v[3] - bf2f(hi.w));
        ((ushort4*)Xh)[idx] = hi;
        ((ushort4*)Xl)[idx] = lo;
    }
}

// ---------------------------------------------------------------------------
// convert_w: transpose w[n][d][e] -> Wt[e'][d], split hi/lo bf16. (unchanged)
// ---------------------------------------------------------------------------
__global__ __launch_bounds__(256) void convert_w(
    const float* __restrict__ wk, const float* __restrict__ wq, const float* __restrict__ wv,
    ushort_t* __restrict__ Bqh, ushort_t* __restrict__ Bql, ushort_t* __restrict__ Bvh)
{
    __shared__ float Ts[64][65];
    const int bid = blockIdx.x;
    const int mat = bid >> 8;
    const int rem = bid & 255;
    const int n  = rem >> 4;
    const int dt = rem & 15;
    const float* w = (mat == 0) ? wq : (mat == 1) ? wk : wv;
    const int tid = threadIdx.x;

    #pragma unroll
    for (int t = 0; t < 16; t++) {
        int i = tid + t * 256;
        int r = i >> 6, e = i & 63;
        Ts[r][e] = w[((size_t)n * 1024 + dt * 64 + r) * 64 + e];
    }
    __syncthreads();
    #pragma unroll
    for (int t = 0; t < 16; t++) {
        int i = tid + t * 256;
        int e = i >> 6, r = i & 63;
        float v = Ts[r][e];
        ushort_t hi = f2bf(v);
        size_t o = (size_t)(n * 64 + e) * 1024 + dt * 64 + r;
        if (mat < 2) {
            Bqh[(size_t)mat * 1048576 + o] = hi;
            Bql[(size_t)mat * 1048576 + o] = f2bf(v - bf2f(hi));
        } else {
            Bvh[o] = hi;
        }
    }
}

// ---------------------------------------------------------------------------
// proj_qk: 3-pass split-bf16 MFMA GEMM, 512 threads (r23-proven).
// ---------------------------------------------------------------------------
__global__ __launch_bounds__(512, 4) void proj_qk(
    const ushort_t* __restrict__ Xh, const ushort_t* __restrict__ Xl,
    const ushort_t* __restrict__ Bh, const ushort_t* __restrict__ Bl,
    float* __restrict__ Qf, ushort_t* __restrict__ Khi, ushort_t* __restrict__ Klo)
{
    __shared__ __align__(16) ushort_t Ah[128 * 64];
    __shared__ __align__(16) ushort_t Al[128 * 64];
    __shared__ __align__(16) ushort_t Bhs[128 * 64];
    __shared__ __align__(16) ushort_t Bls[128 * 64];

    const int mt = blockIdx.x, nt = blockIdx.y;
    const int tid = threadIdx.x;                 // 0..511
    const int w = tid >> 6, lane = tid & 63, col = lane & 15, quad = lane >> 4;
    const int wm = w & 1, wn = w >> 1;           // wm 0..1 (64-row half), wn 0..3 (32-col quarter)

    f32x4 acc[4][2] = {};

    for (int kc = 0; kc < 1024; kc += 64) {
        __syncthreads();
        #pragma unroll
        for (int i = 0; i < 2; i++) {
            int s = (w * 2 + i) * 64 + lane;     // granule 0..1023
            int r = s >> 3, j = s & 7, g = j ^ (r & 7);
            size_t aoff = (size_t)(mt * 128 + r) * 1024 + kc + g * 8;
            size_t boff = (size_t)(nt * 128 + r) * 1024 + kc + g * 8;
            GLOAD_LDS16(Xh + aoff, Ah  + (size_t)(w * 2 + i) * 512);
            GLOAD_LDS16(Xl + aoff, Al  + (size_t)(w * 2 + i) * 512);
            GLOAD_LDS16(Bh + boff, Bhs + (size_t)(w * 2 + i) * 512);
            GLOAD_LDS16(Bl + boff, Bls + (size_t)(w * 2 + i) * 512);
        }
        __syncthreads();
        #pragma unroll
        for (int kk = 0; kk < 2; kk++) {
            bf16x8 a_h[4], a_l[4], b_h[2], b_l[2];
            const int gi = kk * 4 + quad;
            #pragma unroll
            for (int t = 0; t < 4; t++) {
                int rA = wm * 64 + t * 16 + col;
                int jA = gi ^ (rA & 7);
                a_h[t] = *(const bf16x8*)&Ah[(rA * 8 + jA) * 8];
                a_l[t] = *(const bf16x8*)&Al[(rA * 8 + jA) * 8];
            }
            #pragma unroll
            for (int u = 0; u < 2; u++) {
                int rB = wn * 32 + u * 16 + col;
                int jB = gi ^ (rB & 7);
                b_h[u] = *(const bf16x8*)&Bhs[(rB * 8 + jB) * 8];
                b_l[u] = *(const bf16x8*)&Bls[(rB * 8 + jB) * 8];
            }
            #pragma unroll
            for (int t = 0; t < 4; t++)
                #pragma unroll
                for (int u = 0; u < 2; u++) {
                    acc[t][u] = MFMA16(a_h[t], b_h[u], acc[t][u]);
                    acc[t][u] = MFMA16(a_l[t], b_h[u], acc[t][u]);
                    acc[t][u] = MFMA16(a_h[t], b_l[u], acc[t][u]);
                }
        }
    }

    const bool isQ = (nt < 8);
    #pragma unroll
    for (int t = 0; t < 4; t++) {
        #pragma unroll
        for (int u = 0; u < 2; u++) {
            int np = nt * 128 + wn * 32 + u * 16 + col;
            int head = (np >> 6) & 15, e = np & 63;
            #pragma unroll
            for (int rr = 0; rr < 4; rr++) {
                int mm = mt * 128 + wm * 64 + t * 16 + quad * 4 + rr;
                int bi = mm >> 11, l = mm & 2047;
                size_t base = (((size_t)bi * NHEADS + head) * SEQ + l) * HD + e;
                float v = acc[t][u][rr];
                if (isQ) {
                    Qf[base] = v;
                } else {
                    ushort_t hi = f2bf(v);
                    Khi[base] = hi;
                    Klo[base] = f2bf(v - bf2f(hi));
                }
            }
        }
    }
}

// ---------------------------------------------------------------------------
// proj_v: 1-pass bf16, operand-swapped for transposed-V output. (unchanged)
// ---------------------------------------------------------------------------
__global__ __launch_bounds__(256) void proj_v(
    const ushort_t* __restrict__ Wvh, const ushort_t* __restrict__ Xh,
    ushort_t* __restrict__ Vt)
{
    __shared__ __align__(16) ushort_t Ah[128 * 64];
    __shared__ __align__(16) ushort_t Bhs[128 * 64];

    const int mt = blockIdx.x, nt = blockIdx.y;
    const int tid = threadIdx.x;
    const int w = tid >> 6, lane = tid & 63, col = lane & 15, quad = lane >> 4;
    const int wm = w & 1, wn = w >> 1;

    f32x4 acc[4][4] = {};

    for (int kc = 0; kc < 1024; kc += 64) {
        __syncthreads();
        #pragma unroll
        for (int i = 0; i < 4; i++) {
            int s = (w * 4 + i) * 64 + lane;
            int r = s >> 3, j = s & 7, g = j ^ (r & 7);
            size_t aoff = (size_t)(mt * 128 + r) * 1024 + kc + g * 8;
            size_t boff = (size_t)(nt * 128 + r) * 1024 + kc + g * 8;
            GLOAD_LDS16(Wvh + aoff, Ah  + (size_t)(w * 4 + i) * 512);
            GLOAD_LDS16(Xh  + boff, Bhs + (size_t)(w * 4 + i) * 512);
        }
        __syncthreads();
        #pragma unroll
        for (int kk = 0; kk < 2; kk++) {
            bf16x8 a_h[4], b_h[4];
            const int gi = kk * 4 + quad;
            #pragma unroll
            for (int t = 0; t < 4; t++) {
                int rA = wm * 64 + t * 16 + col;
                a_h[t] = *(const bf16x8*)&Ah[(rA * 8 + (gi ^ (rA & 7))) * 8];
                int rB = wn * 64 + t * 16 + col;
                b_h[t] = *(const bf16x8*)&Bhs[(rB * 8 + (gi ^ (rB & 7))) * 8];
            }
            #pragma unroll
            for (int t = 0; t < 4; t++)
                #pragma unroll
                for (int u = 0; u < 4; u++)
                    acc[t][u] = MFMA16(a_h[t], b_h[u], acc[t][u]);
        }
    }

    #pragma unroll
    for (int t = 0; t < 4; t++) {
        #pragma unroll
        for (int rr = 0; rr < 4; rr++) {
            int ep = mt * 128 + wm * 64 + t * 16 + quad * 4 + rr;
            int head = ep >> 6, e = ep & 63;
            #pragma unroll
            for (int u = 0; u < 4; u++) {
                int lg = nt * 128 + wn * 64 + u * 16 + col;
                int bi = lg >> 11, l = lg & 2047;
                Vt[(((size_t)bi * NHEADS + head) * HD + e) * SEQ + l] = f2bf(acc[t][u][rr]);
            }
        }
    }
}

// ---------------------------------------------------------------------------
// Flash attention, operand-swapped, round-24:
//   Base: r20/r23 best attn (127.5 us: 8 waves, (512,4), XCD remap, gate,
//   skip, single-buffer staging).
//   ONE change: PAIRED staging. Stage chunks 2a and 2a+1 into TWO named
//   buffer sets back-to-back, ONE barrier pair per 2 chunks, then compute
//   both sequentially with the byte-identical body. Unlike dbuf (r21/r12,
//   closed: stage/compute interleave grew live state -> occupancy loss),
//   no stage overlaps compute: the two CHUNK_COMPUTEs reuse the same
//   registers sequentially -> VGPR stays ~52. Halves barrier events and
//   amortizes one vmcnt drain over two chunks' compute. LDS 24->48 KB is
//   free: occupancy is wave-capped at 2 blocks/CU (4 waves/EU x 512thr),
//   2 x 48 KB <= 160 KB. 32 chunks = 16 pairs, no tail.
// ---------------------------------------------------------------------------
__global__ __launch_bounds__(512, 4) void attn_mfma_kernel(
    const float* __restrict__ Qf, const ushort_t* __restrict__ Khi,
    const ushort_t* __restrict__ Klo, const ushort_t* __restrict__ Vt,
    float* __restrict__ out)
{
    __shared__ __align__(16) ushort_t Khs0[64 * 64];
    __shared__ __align__(16) ushort_t Kls0[64 * 64];
    __shared__ __align__(16) ushort_t Vts0[64 * 64];
    __shared__ __align__(16) ushort_t Khs1[64 * 64];
    __shared__ __align__(16) ushort_t Kls1[64 * 64];
    __shared__ __align__(16) ushort_t Vts1[64 * 64];

    // XCD-aware remap: all qt-blocks of one bn on one XCD (r20-proven,
    // FETCH 215->41 MB)
    const int linear = blockIdx.y * 16 + blockIdx.x;
    const int xcd = linear & 7;
    const int kk_ = linear >> 3;            // 0..127
    const int bn  = xcd + 8 * (kk_ >> 4);   // 0..63
    const int qt  = kk_ & 15;               // 0..15
    const int tid = threadIdx.x;      // 0..511
    const int w    = tid >> 6;        // 0..7
    const int lane = tid & 63;
    const int col  = lane & 15;
    const int quad = lane >> 4;

    const ushort_t* Kh_g = Khi + (size_t)bn * SEQ * HD;
    const ushort_t* Kl_g = Klo + (size_t)bn * SEQ * HD;
    const ushort_t* Vt_g = Vt  + (size_t)bn * HD * SEQ;

    // ---- Q fragments (B operand: n=lane&15=qrow, k=quad*8+j=e), scaled by
    //      log2e/sqrt(64), split hi/lo.
    union { bf16x8 v; short s[8]; } qh[2], ql[2];
    {
        const int qrow = qt * 128 + w * 16 + col;
        const float* qp = Qf + ((size_t)bn * SEQ + qrow) * HD;
        #pragma unroll
        for (int ks = 0; ks < 2; ks++) {
            float qv[8];
            f32x4 a = *(const f32x4*)(qp + ks * 32 + quad * 8);
            f32x4 b = *(const f32x4*)(qp + ks * 32 + quad * 8 + 4);
            qv[0]=a[0]; qv[1]=a[1]; qv[2]=a[2]; qv[3]=a[3];
            qv[4]=b[0]; qv[5]=b[1]; qv[6]=b[2]; qv[7]=b[3];
            #pragma unroll
            for (int j = 0; j < 8; j++) {
                float xsc = qv[j] * (0.125f * 1.44269504088896f);   // log2e/sqrt(64)
                ushort_t hi = f2bf(xsc);
                ushort_t lo = f2bf(xsc - bf2f(hi));
                qh[ks].s[j] = (short)hi;
                ql[ks].s[j] = (short)lo;
            }
        }
    }

    f32x4 O[4] = {};                                      // O^T: [e-tile]
    float m_i = -1e30f;                                   // per-lane (qrow=col)
    float L   = 0.f;                                      // per-lane partial denom

// issue one chunk's 3 async loads (granule G = tid) into the given buffers
#define STAGE(CH, KHD, KLD, VTD) do {                                         \
    int G_   = tid;                                                           \
    int key_ = G_ >> 3;                                                       \
    int blk_ = (G_ & 7) ^ (key_ & 7);                                         \
    size_t koff_ = (size_t)((CH) * 64 + key_) * HD + blk_ * 8;                \
    size_t voff_ = (size_t)key_ * SEQ + (CH) * 64 + blk_ * 8;                 \
    GLOAD_LDS16(Kh_g + koff_, (KHD) + w * 512);                               \
    GLOAD_LDS16(Kl_g + koff_, (KLD) + w * 512);                               \
    GLOAD_LDS16(Vt_g + voff_, (VTD) + w * 512);                               \
} while (0)

// full per-chunk compute from the given buffer set (identical to r20 body)
#define CHUNK_COMPUTE(KHS, KLS, VTS) do {                                     \
    f32x4 St[4] = {};                                                         \
    _Pragma("unroll")                                                         \
    for (int ks = 0; ks < 2; ks++) {                                          \
        _Pragma("unroll")                                                     \
        for (int t = 0; t < 4; t++) {                                         \
            int key = t * 16 + col;                                           \
            int g = key * 8 + ((ks * 4 + quad) ^ (key & 7));                  \
            bf16x8 kh = *(const bf16x8*)&(KHS)[g * 8];                        \
            St[t] = MFMA16(kh, qh[ks].v, St[t]);                              \
        }                                                                     \
    }                                                                         \
    float mx = St[0][0];                                                      \
    _Pragma("unroll")                                                         \
    for (int t = 0; t < 4; t++)                                               \
        _Pragma("unroll")                                                     \
        for (int r = 0; r < 4; r++) mx = fmaxf(mx, St[t][r]);                 \
    mx = fmaxf(mx, __shfl_xor(mx, 16));                                       \
    mx = fmaxf(mx, __shfl_xor(mx, 32));                                       \
    if (__any(mx > m_i - 46.0f)) {                                            \
        _Pragma("unroll")                                                     \
        for (int ks = 0; ks < 2; ks++) {                                      \
            _Pragma("unroll")                                                 \
            for (int t = 0; t < 4; t++) {                                     \
                int key = t * 16 + col;                                       \
                int g = key * 8 + ((ks * 4 + quad) ^ (key & 7));              \
                bf16x8 kh = *(const bf16x8*)&(KHS)[g * 8];                    \
                bf16x8 kl = *(const bf16x8*)&(KLS)[g * 8];                    \
                St[t] = MFMA16(kh, ql[ks].v, St[t]);                          \
                St[t] = MFMA16(kl, qh[ks].v, St[t]);                          \
            }                                                                 \
        }                                                                     \
        float mxe = St[0][0];                                                 \
        _Pragma("unroll")                                                     \
        for (int t = 0; t < 4; t++)                                           \
            _Pragma("unroll")                                                 \
            for (int r = 0; r < 4; r++) mxe = fmaxf(mxe, St[t][r]);           \
        mxe = fmaxf(mxe, __shfl_xor(mxe, 16));                                \
        mxe = fmaxf(mxe, __shfl_xor(mxe, 32));                                \
        float mnew = fmaxf(m_i, mxe);                                         \
        float al   = fast_exp2(m_i - mnew);                                   \
        m_i = mnew;                                                           \
        bf16x4 vfrag[4][4];                                                   \
        _Pragma("unroll")                                                     \
        for (int u = 0; u < 4; u++) {                                         \
            int rowbase = (u * 16 + col) * 64;                                \
            _Pragma("unroll")                                                 \
            for (int t = 0; t < 4; t++) {                                     \
                int g = (t * 2 + (quad >> 1)) ^ (col & 7);                    \
                vfrag[u][t] = *(const bf16x4*)&(VTS)[rowbase + g * 8 + (quad & 1) * 4]; \
            }                                                                 \
        }                                                                     \
        float psum = 0.f;                                                     \
        bf16x4 pf[4];                                                         \
        _Pragma("unroll")                                                     \
        for (int t = 0; t < 4; t++) {                                         \
            float p0 = fast_exp2(St[t][0] - mnew);                            \
            float p1 = fast_exp2(St[t][1] - mnew);                            \
            float p2 = fast_exp2(St[t][2] - mnew);                            \
            float p3 = fast_exp2(St[t][3] - mnew);                            \
            psum += trunc_bf(p0) + trunc_bf(p1) + trunc_bf(p2) + trunc_bf(p3);\
            union { unsigned u[2]; bf16x4 v; } pk;                            \
            pk.u[0] = pack_bf16_trunc(p0, p1);                                \
            pk.u[1] = pack_bf16_trunc(p2, p3);                                \
            pf[t] = pk.v;                                                     \
        }                                                                     \
        L = L * al + psum;                                                    \
        _Pragma("unroll")                                                     \
        for (int u = 0; u < 4; u++) {                                         \
            O[u][0] *= al; O[u][1] *= al;                                     \
            O[u][2] *= al; O[u][3] *= al;                                     \
        }                                                                     \
        _Pragma("unroll")                                                     \
        for (int t = 0; t < 4; t++)                                           \
            _Pragma("unroll")                                                 \
            for (int u = 0; u < 4; u++)                                       \
                O[u] = MFMA_PV(vfrag[u][t], pf[t], O[u]);                     \
    }                                                                         \
} while (0)

    // 16 pairs of chunks; one barrier pair per TWO chunks.
    for (int pr = 0; pr < 16; pr++) {
        __syncthreads();                       // previous pair fully consumed
        STAGE(2 * pr,     Khs0, Kls0, Vts0);
        STAGE(2 * pr + 1, Khs1, Kls1, Vts1);
        __syncthreads();                       // both buffers visible
        CHUNK_COMPUTE(Khs0, Kls0, Vts0);       // chunk 2*pr
        CHUNK_COMPUTE(Khs1, Kls1, Vts1);       // chunk 2*pr+1
    }

#undef STAGE
#undef CHUNK_COMPUTE

    // ---- epilogue: finish L across quads (2 shuffles), write float4 along e
    const int b = bn >> 4, n = bn & 15;
    {
        float Lr = L;
        Lr += __shfl_xor(Lr, 16);
        Lr += __shfl_xor(Lr, 32);
        float inv = 1.0f / Lr;
        int l = qt * 128 + w * 16 + col;
        size_t base = ((size_t)(b * SEQ + l)) * (NHEADS * HD) + n * HD;
        #pragma unroll
        for (int u = 0; u < 4; u++) {
            f32x4 o;
            o[0] = O[u][0] * inv; o[1] = O[u][1] * inv;
            o[2] = O[u][2] * inv; o[3] = O[u][3] * inv;
            *(f32x4*)&out[base + u * 16 + quad * 4] = o;
        }
    }
}

// ---------------------------------------------------------------------------
extern "C" void kernel_launch(void* const* d_in, const int* in_sizes, int n_in,
                              void* d_out, int out_size, void* d_ws, size_t ws_size,
                              hipStream_t stream) {
    const float* x  = (const float*)d_in[0];
    const float* wk = (const float*)d_in[1];
    const float* wq = (const float*)d_in[2];
    const float* wv = (const float*)d_in[3];
    float* out = (float*)d_out;

    // ws layout (111 MB): Xh | Xl (aliased by Vt after proj_qk) | Bqh | Bql | Bvh | Qf | Khi | Klo
    ushort_t* Xh  = (ushort_t*)d_ws;
    ushort_t* Xl  = Xh + NM;
    ushort_t* Vt  = Xl;                      // alias: Xl dead once proj_qk finishes
    ushort_t* Bqh = Xl + NM;                 // [2048][1024]
    ushort_t* Bql = Bqh + 2097152;
    ushort_t* Bvh = Bql + 2097152;           // [1024][1024]
    float*    Qf  = (float*)(Bvh + 1048576);
    ushort_t* Khi = (ushort_t*)(Qf + NM);
    ushort_t* Klo = Khi + NM;

    convert_x<<<2048, 256, 0, stream>>>(x, Xh, Xl);
    convert_w<<<768, 256, 0, stream>>>(wk, wq, wv, Bqh, Bql, Bvh);
    proj_qk<<<dim3(64, 16), 512, 0, stream>>>(Xh, Xl, Bqh, Bql, Qf, Khi, Klo);
    proj_v<<<dim3(8, 64), 256, 0, stream>>>(Bvh, Xh, Vt);
    attn_mfma_kernel<<<dim3(16, 64), 512, 0, stream>>>(Qf, Khi, Klo, Vt, out);
}

// Round 16
// 313.337 us; speedup vs baseline: 1.6184x; 1.0110x over previous
//
#include <hip/hip_runtime.h>
#include <math.h>

#define DIMX   1024
#define NHEADS 16
#define HD     64
#define BATCH  4
#define SEQ    2048
#define NM     (BATCH * NHEADS * SEQ * HD)   // 8388608 elems per Q/K/V tensor

typedef unsigned short ushort_t;
typedef __attribute__((ext_vector_type(8))) short bf16x8;
typedef __attribute__((ext_vector_type(4))) short bf16x4;
typedef __attribute__((ext_vector_type(4))) float f32x4;

#define MFMA16(a, b, c) __builtin_amdgcn_mfma_f32_16x16x32_bf16(a, b, c, 0, 0, 0)

// K=16 bf16 MFMA (A,B = 4 bf16 each). gfx90a+ "_1k" builtin; asm fallback.
#if __has_builtin(__builtin_amdgcn_mfma_f32_16x16x16bf16_1k)
#define MFMA_PV(a, b, c) __builtin_amdgcn_mfma_f32_16x16x16bf16_1k(a, b, c, 0, 0, 0)
#else
static __device__ __forceinline__ f32x4 mfma_pv_asm(bf16x4 a, bf16x4 b, f32x4 c) {
    asm("v_mfma_f32_16x16x16_bf16 %0, %1, %2, %0" : "+v"(c) : "v"(a), "v"(b));
    return c;
}
#define MFMA_PV(a, b, c) mfma_pv_asm(a, b, c)
#endif

// round-to-nearest-even fp32 -> bf16 bits
__device__ __forceinline__ ushort_t f2bf(float x) {
    unsigned u = __float_as_uint(x);
    u += 0x7fffu + ((u >> 16) & 1u);
    return (ushort_t)(u >> 16);
}
__device__ __forceinline__ float bf2f(ushort_t h) {
    return __uint_as_float(((unsigned)h) << 16);
}

// pack two fp32 -> two TRUNCATED bf16 in one dword (lo in low half).
// v_perm_b32: sel bytes 0-3 pick from src1 (=b), 4-7 from src0 (=a).
__device__ __forceinline__ unsigned pack_bf16_trunc(float lo, float hi) {
#if __has_builtin(__builtin_amdgcn_perm)
    return __builtin_amdgcn_perm(__float_as_uint(hi), __float_as_uint(lo), 0x07060302u);
#else
    return (__float_as_uint(lo) >> 16) | (__float_as_uint(hi) & 0xFFFF0000u);
#endif
}
__device__ __forceinline__ float trunc_bf(float x) {
    return __uint_as_float(__float_as_uint(x) & 0xFFFF0000u);
}

// raw v_exp_f32 (no ocml edge-case wrapper) — guarded
__device__ __forceinline__ float fast_exp2(float x) {
#if __has_builtin(__builtin_amdgcn_exp2f)
    return __builtin_amdgcn_exp2f(x);
#else
    return exp2f(x);
#endif
}

// async global->LDS, 16B per lane; LDS base wave-uniform (HW adds lane*16)
#define GLOAD_LDS16(g, l) \
    __builtin_amdgcn_global_load_lds((const __attribute__((address_space(1))) unsigned int*)(g), \
                                     (__attribute__((address_space(3))) unsigned int*)(l), 16, 0, 0)

// ---------------------------------------------------------------------------
// convert_x: split x fp32 -> Xhi, Xlo bf16.  (unchanged)
// ---------------------------------------------------------------------------
__global__ __launch_bounds__(256) void convert_x(
    const float* __restrict__ x, ushort_t* __restrict__ Xh, ushort_t* __restrict__ Xl)
{
    int i = blockIdx.x * 256 + threadIdx.x;
    #pragma unroll
    for (int t = 0; t < 4; t++) {
        int idx = t * 524288 + i;
        f32x4 v = ((const f32x4*)x)[idx];
        ushort4 hi, lo;
        hi.x = f2bf(v[0]); lo.x = f2bf(v[0] - bf2f(hi.x));
        hi.y = f2bf(v[1]); lo.y = f2bf(v[1] - bf2f(hi.y));
        hi.z = f2bf(v[2]); lo.z = f2bf(v[2] - bf2f(hi.z));
        hi.w = f2bf(v[3]); lo.w = f2bf(v[3] - bf2f(hi.w));
        ((ushort4*)Xh)[idx] = hi;
        ((ushort4*)Xl)[idx] = lo;
    }
}

// ---------------------------------------------------------------------------
// convert_w: transpose w[n][d][e] -> Wt[e'][d], split hi/lo bf16. (unchanged)
// ---------------------------------------------------------------------------
__global__ __launch_bounds__(256) void convert_w(
    const float* __restrict__ wk, const float* __restrict__ wq, const float* __restrict__ wv,
    ushort_t* __restrict__ Bqh, ushort_t* __restrict__ Bql, ushort_t* __restrict__ Bvh)
{
    __shared__ float Ts[64][65];
    const int bid = blockIdx.x;
    const int mat = bid >> 8;
    const int rem = bid & 255;
    const int n  = rem >> 4;
    const int dt = rem & 15;
    const float* w = (mat == 0) ? wq : (mat == 1) ? wk : wv;
    const int tid = threadIdx.x;

    #pragma unroll
    for (int t = 0; t < 16; t++) {
        int i = tid + t * 256;
        int r = i >> 6, e = i & 63;
        Ts[r][e] = w[((size_t)n * 1024 + dt * 64 + r) * 64 + e];
    }
    __syncthreads();
    #pragma unroll
    for (int t = 0; t < 16; t++) {
        int i = tid + t * 256;
        int e = i >> 6, r = i & 63;
        float v = Ts[r][e];
        ushort_t hi = f2bf(v);
        size_t o = (size_t)(n * 64 + e) * 1024 + dt * 64 + r;
        if (mat < 2) {
            Bqh[(size_t)mat * 1048576 + o] = hi;
            Bql[(size_t)mat * 1048576 + o] = f2bf(v - bf2f(hi));
        } else {
            Bvh[o] = hi;
        }
    }
}

// ---------------------------------------------------------------------------
// proj_qk: 3-pass split-bf16 MFMA GEMM, 512 threads (r23-proven).
// ---------------------------------------------------------------------------
__global__ __launch_bounds__(512, 4) void proj_qk(
    const ushort_t* __restrict__ Xh, const ushort_t* __restrict__ Xl,
    const ushort_t* __restrict__ Bh, const ushort_t* __restrict__ Bl,
    float* __restrict__ Qf, ushort_t* __restrict__ Khi, ushort_t* __restrict__ Klo)
{
    __shared__ __align__(16) ushort_t Ah[128 * 64];
    __shared__ __align__(16) ushort_t Al[128 * 64];
    __shared__ __align__(16) ushort_t Bhs[128 * 64];
    __shared__ __align__(16) ushort_t Bls[128 * 64];

    const int mt = blockIdx.x, nt = blockIdx.y;
    const int tid = threadIdx.x;                 // 0..511
    const int w = tid >> 6, lane = tid & 63, col = lane & 15, quad = lane >> 4;
    const int wm = w & 1, wn = w >> 1;           // wm 0..1 (64-row half), wn 0..3 (32-col quarter)

    f32x4 acc[4][2] = {};

    for (int kc = 0; kc < 1024; kc += 64) {
        __syncthreads();
        #pragma unroll
        for (int i = 0; i < 2; i++) {
            int s = (w * 2 + i) * 64 + lane;     // granule 0..1023
            int r = s >> 3, j = s & 7, g = j ^ (r & 7);
            size_t aoff = (size_t)(mt * 128 + r) * 1024 + kc + g * 8;
            size_t boff = (size_t)(nt * 128 + r) * 1024 + kc + g * 8;
            GLOAD_LDS16(Xh + aoff, Ah  + (size_t)(w * 2 + i) * 512);
            GLOAD_LDS16(Xl + aoff, Al  + (size_t)(w * 2 + i) * 512);
            GLOAD_LDS16(Bh + boff, Bhs + (size_t)(w * 2 + i) * 512);
            GLOAD_LDS16(Bl + boff, Bls + (size_t)(w * 2 + i) * 512);
        }
        __syncthreads();
        #pragma unroll
        for (int kk = 0; kk < 2; kk++) {
            bf16x8 a_h[4], a_l[4], b_h[2], b_l[2];
            const int gi = kk * 4 + quad;
            #pragma unroll
            for (int t = 0; t < 4; t++) {
                int rA = wm * 64 + t * 16 + col;
                int jA = gi ^ (rA & 7);
                a_h[t] = *(const bf16x8*)&Ah[(rA * 8 + jA) * 8];
                a_l[t] = *(const bf16x8*)&Al[(rA * 8 + jA) * 8];
            }
            #pragma unroll
            for (int u = 0; u < 2; u++) {
                int rB = wn * 32 + u * 16 + col;
                int jB = gi ^ (rB & 7);
                b_h[u] = *(const bf16x8*)&Bhs[(rB * 8 + jB) * 8];
                b_l[u] = *(const bf16x8*)&Bls[(rB * 8 + jB) * 8];
            }
            #pragma unroll
            for (int t = 0; t < 4; t++)
                #pragma unroll
                for (int u = 0; u < 2; u++) {
                    acc[t][u] = MFMA16(a_h[t], b_h[u], acc[t][u]);
                    acc[t][u] = MFMA16(a_l[t], b_h[u], acc[t][u]);
                    acc[t][u] = MFMA16(a_h[t], b_l[u], acc[t][u]);
                }
        }
    }

    const bool isQ = (nt < 8);
    #pragma unroll
    for (int t = 0; t < 4; t++) {
        #pragma unroll
        for (int u = 0; u < 2; u++) {
            int np = nt * 128 + wn * 32 + u * 16 + col;
            int head = (np >> 6) & 15, e = np & 63;
            #pragma unroll
            for (int rr = 0; rr < 4; rr++) {
                int mm = mt * 128 + wm * 64 + t * 16 + quad * 4 + rr;
                int bi = mm >> 11, l = mm & 2047;
                size_t base = (((size_t)bi * NHEADS + head) * SEQ + l) * HD + e;
                float v = acc[t][u][rr];
                if (isQ) {
                    Qf[base] = v;
                } else {
                    ushort_t hi = f2bf(v);
                    Khi[base] = hi;
                    Klo[base] = f2bf(v - bf2f(hi));
                }
            }
        }
    }
}

// ---------------------------------------------------------------------------
// proj_v: 1-pass bf16, operand-swapped. Round-25: 512 threads (8 waves),
//   the r23 lever applied to proj_v. Per-wave output 64x32 (acc[4][2],
//   ~100 VGPR <= 128 cap of (512,4)); staging 2 instr/tensor/thread;
//   occupancy 3 waves/SIMD -> 4. Same per-element MFMA order ->
//   bit-identical Vt.
// ---------------------------------------------------------------------------
__global__ __launch_bounds__(512, 4) void proj_v(
    const ushort_t* __restrict__ Wvh, const ushort_t* __restrict__ Xh,
    ushort_t* __restrict__ Vt)
{
    __shared__ __align__(16) ushort_t Ah[128 * 64];
    __shared__ __align__(16) ushort_t Bhs[128 * 64];

    const int mt = blockIdx.x, nt = blockIdx.y;
    const int tid = threadIdx.x;                 // 0..511
    const int w = tid >> 6, lane = tid & 63, col = lane & 15, quad = lane >> 4;
    const int wm = w & 1, wn = w >> 1;           // wm 0..1 (A 64-row half), wn 0..3 (B 32-row quarter)

    f32x4 acc[4][2] = {};

    for (int kc = 0; kc < 1024; kc += 64) {
        __syncthreads();
        #pragma unroll
        for (int i = 0; i < 2; i++) {
            int s = (w * 2 + i) * 64 + lane;     // granule 0..1023
            int r = s >> 3, j = s & 7, g = j ^ (r & 7);
            size_t aoff = (size_t)(mt * 128 + r) * 1024 + kc + g * 8;
            size_t boff = (size_t)(nt * 128 + r) * 1024 + kc + g * 8;
            GLOAD_LDS16(Wvh + aoff, Ah  + (size_t)(w * 2 + i) * 512);
            GLOAD_LDS16(Xh  + boff, Bhs + (size_t)(w * 2 + i) * 512);
        }
        __syncthreads();
        #pragma unroll
        for (int kk = 0; kk < 2; kk++) {
            bf16x8 a_h[4], b_h[2];
            const int gi = kk * 4 + quad;
            #pragma unroll
            for (int t = 0; t < 4; t++) {
                int rA = wm * 64 + t * 16 + col;
                a_h[t] = *(const bf16x8*)&Ah[(rA * 8 + (gi ^ (rA & 7))) * 8];
            }
            #pragma unroll
            for (int u = 0; u < 2; u++) {
                int rB = wn * 32 + u * 16 + col;
                b_h[u] = *(const bf16x8*)&Bhs[(rB * 8 + (gi ^ (rB & 7))) * 8];
            }
            #pragma unroll
            for (int t = 0; t < 4; t++)
                #pragma unroll
                for (int u = 0; u < 2; u++)
                    acc[t][u] = MFMA16(a_h[t], b_h[u], acc[t][u]);
        }
    }

    #pragma unroll
    for (int t = 0; t < 4; t++) {
        #pragma unroll
        for (int rr = 0; rr < 4; rr++) {
            int ep = mt * 128 + wm * 64 + t * 16 + quad * 4 + rr;
            int head = ep >> 6, e = ep & 63;
            #pragma unroll
            for (int u = 0; u < 2; u++) {
                int lg = nt * 128 + wn * 32 + u * 16 + col;
                int bi = lg >> 11, l = lg & 2047;
                Vt[(((size_t)bi * NHEADS + head) * HD + e) * SEQ + l] = f2bf(acc[t][u][rr]);
            }
        }
    }
}

// ---------------------------------------------------------------------------
// Flash attention, operand-swapped — round-24 version (best: 316.8 total).
// 8 waves/block, (512,4), XCD remap, two-stage QK gate, negligible-chunk
// skip, PAIRED single-issue staging (one barrier pair per 2 chunks).
// Unchanged this round.
// ---------------------------------------------------------------------------
__global__ __launch_bounds__(512, 4) void attn_mfma_kernel(
    const float* __restrict__ Qf, const ushort_t* __restrict__ Khi,
    const ushort_t* __restrict__ Klo, const ushort_t* __restrict__ Vt,
    float* __restrict__ out)
{
    __shared__ __align__(16) ushort_t Khs0[64 * 64];
    __shared__ __align__(16) ushort_t Kls0[64 * 64];
    __shared__ __align__(16) ushort_t Vts0[64 * 64];
    __shared__ __align__(16) ushort_t Khs1[64 * 64];
    __shared__ __align__(16) ushort_t Kls1[64 * 64];
    __shared__ __align__(16) ushort_t Vts1[64 * 64];

    // XCD-aware remap: all qt-blocks of one bn on one XCD (r20-proven,
    // FETCH 215->41 MB)
    const int linear = blockIdx.y * 16 + blockIdx.x;
    const int xcd = linear & 7;
    const int kk_ = linear >> 3;            // 0..127
    const int bn  = xcd + 8 * (kk_ >> 4);   // 0..63
    const int qt  = kk_ & 15;               // 0..15
    const int tid = threadIdx.x;      // 0..511
    const int w    = tid >> 6;        // 0..7
    const int lane = tid & 63;
    const int col  = lane & 15;
    const int quad = lane >> 4;

    const ushort_t* Kh_g = Khi + (size_t)bn * SEQ * HD;
    const ushort_t* Kl_g = Klo + (size_t)bn * SEQ * HD;
    const ushort_t* Vt_g = Vt  + (size_t)bn * HD * SEQ;

    // ---- Q fragments (B operand: n=lane&15=qrow, k=quad*8+j=e), scaled by
    //      log2e/sqrt(64), split hi/lo.
    union { bf16x8 v; short s[8]; } qh[2], ql[2];
    {
        const int qrow = qt * 128 + w * 16 + col;
        const float* qp = Qf + ((size_t)bn * SEQ + qrow) * HD;
        #pragma unroll
        for (int ks = 0; ks < 2; ks++) {
            float qv[8];
            f32x4 a = *(const f32x4*)(qp + ks * 32 + quad * 8);
            f32x4 b = *(const f32x4*)(qp + ks * 32 + quad * 8 + 4);
            qv[0]=a[0]; qv[1]=a[1]; qv[2]=a[2]; qv[3]=a[3];
            qv[4]=b[0]; qv[5]=b[1]; qv[6]=b[2]; qv[7]=b[3];
            #pragma unroll
            for (int j = 0; j < 8; j++) {
                float xsc = qv[j] * (0.125f * 1.44269504088896f);   // log2e/sqrt(64)
                ushort_t hi = f2bf(xsc);
                ushort_t lo = f2bf(xsc - bf2f(hi));
                qh[ks].s[j] = (short)hi;
                ql[ks].s[j] = (short)lo;
            }
        }
    }

    f32x4 O[4] = {};                                      // O^T: [e-tile]
    float m_i = -1e30f;                                   // per-lane (qrow=col)
    float L   = 0.f;                                      // per-lane partial denom

// issue one chunk's 3 async loads (granule G = tid) into the given buffers
#define STAGE(CH, KHD, KLD, VTD) do {                                         \
    int G_   = tid;                                                           \
    int key_ = G_ >> 3;                                                       \
    int blk_ = (G_ & 7) ^ (key_ & 7);                                         \
    size_t koff_ = (size_t)((CH) * 64 + key_) * HD + blk_ * 8;                \
    size_t voff_ = (size_t)key_ * SEQ + (CH) * 64 + blk_ * 8;                 \
    GLOAD_LDS16(Kh_g + koff_, (KHD) + w * 512);                               \
    GLOAD_LDS16(Kl_g + koff_, (KLD) + w * 512);                               \
    GLOAD_LDS16(Vt_g + voff_, (VTD) + w * 512);                               \
} while (0)

// full per-chunk compute from the given buffer set (identical to r20 body)
#define CHUNK_COMPUTE(KHS, KLS, VTS) do {                                     \
    f32x4 St[4] = {};                                                         \
    _Pragma("unroll")                                                         \
    for (int ks = 0; ks < 2; ks++) {                                          \
        _Pragma("unroll")                                                     \
        for (int t = 0; t < 4; t++) {                                         \
            int key = t * 16 + col;                                           \
            int g = key * 8 + ((ks * 4 + quad) ^ (key & 7));                  \
            bf16x8 kh = *(const bf16x8*)&(KHS)[g * 8];                        \
            St[t] = MFMA16(kh, qh[ks].v, St[t]);                              \
        }                                                                     \
    }                                                                         \
    float mx = St[0][0];                                                      \
    _Pragma("unroll")                                                         \
    for (int t = 0; t < 4; t++)                                               \
        _Pragma("unroll")                                                     \
        for (int r = 0; r < 4; r++) mx = fmaxf(mx, St[t][r]);                 \
    mx = fmaxf(mx, __shfl_xor(mx, 16));                                       \
    mx = fmaxf(mx, __shfl_xor(mx, 32));                                       \
    if (__any(mx > m_i - 46.0f)) {                                            \
        _Pragma("unroll")                                                     \
        for (int ks = 0; ks < 2; ks++) {                                      \
            _Pragma("unroll")                                                 \
            for (int t = 0; t < 4; t++) {                                     \
                int key = t * 16 + col;                                       \
                int g = key * 8 + ((ks * 4 + quad) ^ (key & 7));              \
                bf16x8 kh = *(const bf16x8*)&(KHS)[g * 8];                    \
                bf16x8 kl = *(const bf16x8*)&(KLS)[g * 8];                    \
                St[t] = MFMA16(kh, ql[ks].v, St[t]);                          \
                St[t] = MFMA16(kl, qh[ks].v, St[t]);                          \
            }                                                                 \
        }                                                                     \
        float mxe = St[0][0];                                                 \
        _Pragma("unroll")                                                     \
        for (int t = 0; t < 4; t++)                                           \
            _Pragma("unroll")                                                 \
            for (int r = 0; r < 4; r++) mxe = fmaxf(mxe, St[t][r]);           \
        mxe = fmaxf(mxe, __shfl_xor(mxe, 16));                                \
        mxe = fmaxf(mxe, __shfl_xor(mxe, 32));                                \
        float mnew = fmaxf(m_i, mxe);                                         \
        float al   = fast_exp2(m_i - mnew);                                   \
        m_i = mnew;                                                           \
        bf16x4 vfrag[4][4];                                                   \
        _Pragma("unroll")                                                     \
        for (int u = 0; u < 4; u++) {                                         \
            int rowbase = (u * 16 + col) * 64;                                \
            _Pragma("unroll")                                                 \
            for (int t = 0; t < 4; t++) {                                     \
                int g = (t * 2 + (quad >> 1)) ^ (col & 7);                    \
                vfrag[u][t] = *(const bf16x4*)&(VTS)[rowbase + g * 8 + (quad & 1) * 4]; \
            }                                                                 \
        }                                                                     \
        float psum = 0.f;                                                     \
        bf16x4 pf[4];                                                         \
        _Pragma("unroll")                                                     \
        for (int t = 0; t < 4; t++) {                                         \
            float p0 = fast_exp2(St[t][0] - mnew);                            \
            float p1 = fast_exp2(St[t][1] - mnew);                            \
            float p2 = fast_exp2(St[t][2] - mnew);                            \
            float p3 = fast_exp2(St[t][3] - mnew);                            \
            psum += trunc_bf(p0) + trunc_bf(p1) + trunc_bf(p2) + trunc_bf(p3);\
            union { unsigned u[2]; bf16x4 v; } pk;                            \
            pk.u[0] = pack_bf16_trunc(p0, p1);                                \
            pk.u[1] = pack_bf16_trunc(p2, p3);                                \
            pf[t] = pk.v;                                                     \
        }                                                                     \
        L = L * al + psum;                                                    \
        _Pragma("unroll")                                                     \
        for (int u = 0; u < 4; u++) {                                         \
            O[u][0] *= al; O[u][1] *= al;                                     \
            O[u][2] *= al; O[u][3] *= al;                                     \
        }                                                                     \
        _Pragma("unroll")                                                     \
        for (int t = 0; t < 4; t++)                                           \
            _Pragma("unroll")                                                 \
            for (int u = 0; u < 4; u++)                                       \
                O[u] = MFMA_PV(vfrag[u][t], pf[t], O[u]);                     \
    }                                                                         \
} while (0)

    // 16 pairs of chunks; one barrier pair per TWO chunks.
    for (int pr = 0; pr < 16; pr++) {
        __syncthreads();                       // previous pair fully consumed
        STAGE(2 * pr,     Khs0, Kls0, Vts0);
        STAGE(2 * pr + 1, Khs1, Kls1, Vts1);
        __syncthreads();                       // both buffers visible
        CHUNK_COMPUTE(Khs0, Kls0, Vts0);       // chunk 2*pr
        CHUNK_COMPUTE(Khs1, Kls1, Vts1);       // chunk 2*pr+1
    }

#undef STAGE
#undef CHUNK_COMPUTE

    // ---- epilogue: finish L across quads (2 shuffles), write float4 along e
    const int b = bn >> 4, n = bn & 15;
    {
        float Lr = L;
        Lr += __shfl_xor(Lr, 16);
        Lr += __shfl_xor(Lr, 32);
        float inv = 1.0f / Lr;
        int l = qt * 128 + w * 16 + col;
        size_t base = ((size_t)(b * SEQ + l)) * (NHEADS * HD) + n * HD;
        #pragma unroll
        for (int u = 0; u < 4; u++) {
            f32x4 o;
            o[0] = O[u][0] * inv; o[1] = O[u][1] * inv;
            o[2] = O[u][2] * inv; o[3] = O[u][3] * inv;
            *(f32x4*)&out[base + u * 16 + quad * 4] = o;
        }
    }
}

// ---------------------------------------------------------------------------
extern "C" void kernel_launch(void* const* d_in, const int* in_sizes, int n_in,
                              void* d_out, int out_size, void* d_ws, size_t ws_size,
                              hipStream_t stream) {
    const float* x  = (const float*)d_in[0];
    const float* wk = (const float*)d_in[1];
    const float* wq = (const float*)d_in[2];
    const float* wv = (const float*)d_in[3];
    float* out = (float*)d_out;

    // ws layout (111 MB): Xh | Xl (aliased by Vt after proj_qk) | Bqh | Bql | Bvh | Qf | Khi | Klo
    ushort_t* Xh  = (ushort_t*)d_ws;
    ushort_t* Xl  = Xh + NM;
    ushort_t* Vt  = Xl;                      // alias: Xl dead once proj_qk finishes
    ushort_t* Bqh = Xl + NM;                 // [2048][1024]
    ushort_t* Bql = Bqh + 2097152;
    ushort_t* Bvh = Bql + 2097152;           // [1024][1024]
    float*    Qf  = (float*)(Bvh + 1048576);
    ushort_t* Khi = (ushort_t*)(Qf + NM);
    ushort_t* Klo = Khi + NM;

    convert_x<<<2048, 256, 0, stream>>>(x, Xh, Xl);
    convert_w<<<768, 256, 0, stream>>>(wk, wq, wv, Bqh, Bql, Bvh);
    proj_qk<<<dim3(64, 16), 512, 0, stream>>>(Xh, Xl, Bqh, Bql, Qf, Khi, Klo);
    proj_v<<<dim3(8, 64), 512, 0, stream>>>(Bvh, Xh, Vt);
    attn_mfma_kernel<<<dim3(16, 64), 512, 0, stream>>>(Qf, Khi, Klo, Vt, out);
}